// Round 6
// baseline (600.971 us; speedup 1.0000x reference)
//
#include <hip/hip_runtime.h>
#include <math.h>

// ---------------------------------------------------------------------------
// GCN dual-branch, algebraically restructured:
//   ax = A'x  (128 feats)            [A' = D^-1/2 (A+I) D^-1/2]
//   branch1: y16 = relu(ax@W1 + b1) @ (W2@Wc); cls = A'(y16) + (b2@Wc+bc)
//   branch2 (fully linear): g1 = ax@Me + c1 ; g_{k+1} = A'(g_k) + c_{k+1}
//            trust = sigmoid(A'(g3) + be4@Wt + bt)
// Edge weights are never materialized: A'v|_i = d_i*(d_i*v_i + sum dis[s]*v_s),
// dis gathered from the L2-resident 400KB table.
// edge_index is INT32. GEMM on MFMA via split-bf16 (hi+lo).
// ---------------------------------------------------------------------------

#define SM_W2C   0        // 256*16
#define SM_T4    4096     // 128*2
#define SM_T3    4352
#define SM_T2    4608
#define SM_ME    4864
#define SM_CLSC  5120     // 16
#define SM_C1    5136     // 2
#define SM_C2    5138
#define SM_C3    5140
#define SM_FC    5142     // 2  (be4@Wt + bt)
#define SM_TOTAL 5248

typedef __attribute__((ext_vector_type(8))) short bf16x8;
typedef __attribute__((ext_vector_type(4))) float f32x4;
#define MFMA16(a, b, c) __builtin_amdgcn_mfma_f32_16x16x32_bf16(a, b, c, 0, 0, 0)

__device__ inline unsigned short f2bf(float f) {  // RNE f32 -> bf16 bits
  unsigned u = __float_as_uint(f);
  u += 0x7fffu + ((u >> 16) & 1u);
  return (unsigned short)(u >> 16);
}
__device__ inline float bf2f(unsigned short h) {
  return __uint_as_float((unsigned)h << 16);
}

__global__ __launch_bounds__(256) void k_deg(const int* __restrict__ ei,
                                             int* __restrict__ deg, int E, int N) {
  int e = blockIdx.x * 256 + threadIdx.x;
  if (e < E) {
    unsigned c = (unsigned)ei[E + e];
    if (c >= (unsigned)N) c = 0;
    atomicAdd(&deg[c], 1);
  }
}

// phase 1: per-block inclusive scan of deg -> rowptr[i+1] (pre-offset),
// block totals -> bsum; fused dis = rsqrt(deg+1) and cnt=0.
__global__ __launch_bounds__(1024) void k_scan1(const int* __restrict__ deg,
                                                int* __restrict__ rowptr,
                                                int* __restrict__ bsum,
                                                float* __restrict__ dis,
                                                int* __restrict__ cnt, int n) {
  __shared__ int wsum[16];
  int tid = threadIdx.x, lane = tid & 63, wid = tid >> 6;
  int i = blockIdx.x * 1024 + tid;
  int v = (i < n) ? deg[i] : 0;
  if (i < n) {
    dis[i] = 1.0f / sqrtf((float)v + 1.0f);
    cnt[i] = 0;
  }
  int x = v;
  #pragma unroll
  for (int off = 1; off < 64; off <<= 1) {
    int t = __shfl_up(x, off, 64);
    if (lane >= off) x += t;
  }
  if (lane == 63) wsum[wid] = x;
  __syncthreads();
  if (wid == 0 && lane < 16) {
    int ws = wsum[lane];
    #pragma unroll
    for (int off = 1; off < 16; off <<= 1) {
      int t = __shfl_up(ws, off, 64);
      if (lane >= off) ws += t;
    }
    wsum[lane] = ws;
  }
  __syncthreads();
  int incl = x + (wid ? wsum[wid - 1] : 0);
  if (i < n) rowptr[i + 1] = incl;
  if (tid == 0) bsum[blockIdx.x] = wsum[15];
}

// phase 2: exclusive scan of the (<=128) block totals, in place
__global__ __launch_bounds__(128) void k_scan2(int* __restrict__ bsum,
                                               int* __restrict__ rowptr, int B) {
  __shared__ int s[128];
  int tid = threadIdx.x;
  s[tid] = (tid < B) ? bsum[tid] : 0;
  __syncthreads();
  if (tid == 0) {
    int acc = 0;
    for (int j = 0; j < B; ++j) { int t = s[j]; s[j] = acc; acc += t; }
    rowptr[0] = 0;
  }
  __syncthreads();
  if (tid < B) bsum[tid] = s[tid];
}

// phase 3: add block offsets
__global__ __launch_bounds__(256) void k_scan3(int* __restrict__ rowptr,
                                               const int* __restrict__ bsum, int n) {
  int i = blockIdx.x * 256 + threadIdx.x;
  if (i < n) rowptr[i + 1] += bsum[i >> 10];
}

// CSR build: only src indices (weights computed on the fly from dis)
__global__ __launch_bounds__(256) void k_scatter(const int* __restrict__ ei,
                                                 const int* __restrict__ rowptr,
                                                 int* __restrict__ cnt,
                                                 int* __restrict__ csr_src,
                                                 int E, int N) {
  int e = blockIdx.x * 256 + threadIdx.x;
  if (e >= E) return;
  unsigned r = (unsigned)ei[e];
  unsigned c = (unsigned)ei[E + e];
  if (r >= (unsigned)N) r = 0;
  if (c >= (unsigned)N) c = 0;
  int pos = rowptr[c] + atomicAdd(&cnt[c], 1);
  csr_src[pos] = (int)r;
}

// fold weight chains + bf16 hi/lo splits. Grid = 33 blocks.
__global__ __launch_bounds__(256) void k_precompute(
    const float* __restrict__ W1,
    const float* __restrict__ W2, const float* __restrict__ b2,
    const float* __restrict__ Wc, const float* __restrict__ bc,
    const float* __restrict__ We1, const float* __restrict__ be1,
    const float* __restrict__ We2, const float* __restrict__ be2,
    const float* __restrict__ We3, const float* __restrict__ be3,
    const float* __restrict__ We4, const float* __restrict__ be4,
    const float* __restrict__ Wt, const float* __restrict__ bt,
    float* __restrict__ sm,
    unsigned short* __restrict__ w1h, unsigned short* __restrict__ w1l,
    unsigned short* __restrict__ w2h, unsigned short* __restrict__ w2l) {
  int tid = threadIdx.x, b = blockIdx.x;
  if (b < 16) {
    int r = b * 16 + (tid >> 4), c = tid & 15;
    float s = 0.f;
    #pragma unroll 4
    for (int k = 0; k < 128; ++k) s += W2[(size_t)r * 128 + k] * Wc[k * 16 + c];
    sm[SM_W2C + r * 16 + c] = s;
    unsigned short h = f2bf(s);
    w2h[c * 256 + r] = h;                 // w2t[c][k=r]
    w2l[c * 256 + r] = f2bf(s - bf2f(h));
    return;
  }
  if (b < 32) {
    int base = (b - 16) * 2048;
    #pragma unroll
    for (int it = 0; it < 8; ++it) {
      int idx = base + it * 256 + tid;    // w1t[c][k]
      int c = idx >> 7, k = idx & 127;
      float v = W1[(size_t)k * 256 + c];
      unsigned short h = f2bf(v);
      w1h[idx] = h;
      w1l[idx] = f2bf(v - bf2f(h));
    }
    return;
  }
  // b == 32: chains
  {
    int r = tid >> 1, c = tid & 1; float s = 0.f;
    for (int k = 0; k < 128; ++k) s += We4[r * 128 + k] * Wt[k * 2 + c];
    sm[SM_T4 + r * 2 + c] = s;
  }
  __syncthreads();
  {
    int r = tid >> 1, c = tid & 1; float s = 0.f;
    for (int k = 0; k < 128; ++k) s += We3[r * 128 + k] * sm[SM_T4 + k * 2 + c];
    sm[SM_T3 + r * 2 + c] = s;
  }
  __syncthreads();
  {
    int r = tid >> 1, c = tid & 1; float s = 0.f;
    for (int k = 0; k < 128; ++k) s += We2[r * 128 + k] * sm[SM_T3 + k * 2 + c];
    sm[SM_T2 + r * 2 + c] = s;
  }
  __syncthreads();
  {
    int r = tid >> 1, c = tid & 1; float s = 0.f;
    for (int k = 0; k < 128; ++k) s += We1[r * 128 + k] * sm[SM_T2 + k * 2 + c];
    sm[SM_ME + r * 2 + c] = s;
  }
  if (tid < 16) {
    float s = 0.f;
    for (int k = 0; k < 128; ++k) s += b2[k] * Wc[k * 16 + tid];
    sm[SM_CLSC + tid] = s + bc[tid];
  }
  __syncthreads();
  if (tid < 2) {
    float s = 0.f;
    for (int k = 0; k < 128; ++k) s += be1[k] * sm[SM_T2 + k * 2 + tid];
    sm[SM_C1 + tid] = s;
    s = 0.f;
    for (int k = 0; k < 128; ++k) s += be2[k] * sm[SM_T3 + k * 2 + tid];
    sm[SM_C2 + tid] = s;
    s = 0.f;
    for (int k = 0; k < 128; ++k) s += be3[k] * sm[SM_T4 + k * 2 + tid];
    sm[SM_C3 + tid] = s;
    s = 0.f;
    for (int k = 0; k < 128; ++k) s += be4[k] * Wt[k * 2 + tid];
    sm[SM_FC + tid] = s + bt[tid];
  }
}

// ax = A'x (wave per node), bf16 hi/lo out; fused g1 = ax@Me + c1.
// a = d*(d*x_node + sum dis[s]*x_s)
__global__ __launch_bounds__(256) void k_agg128(
    const float* __restrict__ x, const int* __restrict__ rowptr,
    const int* __restrict__ csr_src, const float* __restrict__ dis,
    const float* __restrict__ sm,
    unsigned short* __restrict__ axh, unsigned short* __restrict__ axl,
    float* __restrict__ ga, int N) {
  int node = blockIdx.x * 4 + (threadIdx.x >> 6);
  if (node >= N) return;
  int lane = threadIdx.x & 63;
  const float2* x2 = (const float2*)x;
  float d = dis[node];
  float2 v = x2[(size_t)node * 64 + lane];
  float a0 = d * v.x, a1 = d * v.y;
  int e = rowptr[node], end = rowptr[node + 1];
  while (e < end) {
    int rem = end - e;
    int cnt = rem < 64 ? rem : 64;
    int off = lane < cnt ? lane : cnt - 1;
    int src_l = csr_src[e + off];
    int wbits = __float_as_int(dis[src_l]);   // gather from L2-resident table
    for (int i = 0; i < cnt; ++i) {
      int s = __builtin_amdgcn_readlane(src_l, i);
      float w = __int_as_float(__builtin_amdgcn_readlane(wbits, i));
      float2 u = x2[(size_t)s * 64 + lane];
      a0 = fmaf(w, u.x, a0);
      a1 = fmaf(w, u.y, a1);
    }
    e += 64;
  }
  a0 *= d; a1 *= d;
  unsigned short h0 = f2bf(a0), h1v = f2bf(a1);
  unsigned short l0 = f2bf(a0 - bf2f(h0)), l1 = f2bf(a1 - bf2f(h1v));
  ((unsigned int*)axh)[(size_t)node * 64 + lane] = (unsigned)h0 | ((unsigned)h1v << 16);
  ((unsigned int*)axl)[(size_t)node * 64 + lane] = (unsigned)l0 | ((unsigned)l1 << 16);
  float4 me = *(const float4*)&sm[SM_ME + lane * 4];
  float p0 = a0 * me.x + a1 * me.z;
  float p1 = a0 * me.y + a1 * me.w;
  #pragma unroll
  for (int m = 32; m; m >>= 1) { p0 += __shfl_xor(p0, m); p1 += __shfl_xor(p1, m); }
  if (lane == 0)
    ((float2*)ga)[node] = make_float2(p0 + sm[SM_C1 + 0], p1 + sm[SM_C1 + 1]);
}

// y16 = relu(ax@W1 + b1) @ W2c via split-bf16 MFMA (layouts verified in R4).
__global__ __launch_bounds__(256, 2) void k_gemm_mfma(
    const unsigned short* __restrict__ axh, const unsigned short* __restrict__ axl,
    const unsigned short* __restrict__ w1h, const unsigned short* __restrict__ w1l,
    const unsigned short* __restrict__ w2h, const unsigned short* __restrict__ w2l,
    const float* __restrict__ b1, float* __restrict__ Y, int N) {
  __shared__ unsigned short lds[32768];  // 64 KB
  int tid = threadIdx.x, lane = tid & 63, w = tid >> 6;
  int r16 = lane & 15, kh = lane >> 4;
  int m0 = blockIdx.x * 64;
  #pragma unroll
  for (int it = 0; it < 8; ++it) {
    int idx = it * 256 + tid;            // 0..2047 chunks of 16B
    int arr = idx >> 10, rem = idx & 1023;
    int row = rem >> 4, ch = rem & 15;
    int gr = m0 + row; if (gr > N - 1) gr = N - 1;
    const unsigned short* src = (arr ? axl : axh) + (size_t)gr * 128 + ch * 8;
    uint4 vv = *(const uint4*)src;
    *(uint4*)&lds[arr * 8192 + row * 128 + ((ch ^ (row & 7)) * 8)] = vv;
  }
  __syncthreads();
  f32x4 acc[4][4];
  #pragma unroll
  for (int i = 0; i < 4; ++i)
    #pragma unroll
    for (int j = 0; j < 4; ++j) acc[i][j] = (f32x4){0.f, 0.f, 0.f, 0.f};
  #pragma unroll
  for (int ks = 0; ks < 4; ++ks) {
    bf16x8 bh[4], bl[4];
    #pragma unroll
    for (int nt = 0; nt < 4; ++nt) {
      int col = w * 64 + nt * 16 + r16;
      size_t boff = (size_t)col * 128 + ks * 32 + kh * 8;
      bh[nt] = *(const bf16x8*)(w1h + boff);
      bl[nt] = *(const bf16x8*)(w1l + boff);
    }
    #pragma unroll
    for (int mt = 0; mt < 4; ++mt) {
      int row = mt * 16 + r16;
      int ch = ks * 4 + kh;
      int off = row * 128 + ((ch ^ (row & 7)) * 8);
      bf16x8 ah = *(const bf16x8*)&lds[off];
      bf16x8 al = *(const bf16x8*)&lds[8192 + off];
      #pragma unroll
      for (int nt = 0; nt < 4; ++nt) {
        acc[mt][nt] = MFMA16(ah, bh[nt], acc[mt][nt]);
        acc[mt][nt] = MFMA16(ah, bl[nt], acc[mt][nt]);
        acc[mt][nt] = MFMA16(al, bh[nt], acc[mt][nt]);
      }
    }
  }
  __syncthreads();
  #pragma unroll
  for (int nt = 0; nt < 4; ++nt) {
    int colL = w * 64 + nt * 16 + r16;
    float bv = b1[colL];
    #pragma unroll
    for (int mt = 0; mt < 4; ++mt) {
      #pragma unroll
      for (int r = 0; r < 4; ++r) {
        int rowL = mt * 16 + kh * 4 + r;
        float vv = acc[mt][nt][r] + bv;
        vv = vv > 0.f ? vv : 0.f;
        unsigned short hh = f2bf(vv);
        unsigned short ll = f2bf(vv - bf2f(hh));
        int idx = rowL * 256 + (colL ^ ((rowL & 7) << 3));
        lds[idx] = hh;
        lds[16384 + idx] = ll;
      }
    }
  }
  __syncthreads();
  f32x4 y = (f32x4){0.f, 0.f, 0.f, 0.f};
  int rowL = w * 16 + r16;
  #pragma unroll
  for (int k2 = 0; k2 < 8; ++k2) {
    int cb = k2 * 32 + kh * 8;
    int idx = rowL * 256 + (cb ^ ((rowL & 7) << 3));
    bf16x8 a2h = *(const bf16x8*)&lds[idx];
    bf16x8 a2l = *(const bf16x8*)&lds[16384 + idx];
    size_t boff = (size_t)r16 * 256 + cb;
    bf16x8 b2h = *(const bf16x8*)(w2h + boff);
    bf16x8 b2l = *(const bf16x8*)(w2l + boff);
    y = MFMA16(a2h, b2h, y);
    y = MFMA16(a2h, b2l, y);
    y = MFMA16(a2l, b2h, y);
  }
  #pragma unroll
  for (int r = 0; r < 4; ++r) {
    int gr = m0 + w * 16 + kh * 4 + r;
    if (gr < N) Y[(size_t)gr * 16 + r16] = y[r];
  }
}

// fused: cls = A'(y16) + cls_const -> out, AND gb = A'(ga) + c2 -> gout.
// 16 lanes per node; g-part computed redundantly by all 16 (broadcast loads).
__global__ __launch_bounds__(256) void k_agg18(
    const float* __restrict__ Y, const float* __restrict__ g,
    const int* __restrict__ rowptr, const int* __restrict__ csr_src,
    const float* __restrict__ dis, const float* __restrict__ sm,
    float* __restrict__ out, float* __restrict__ gout, int N) {
  int node = blockIdx.x * 16 + (threadIdx.x >> 4);
  if (node >= N) return;
  int sl = threadIdx.x & 15;
  const float2* g2 = (const float2*)g;
  float d = dis[node];
  float acc = d * Y[(size_t)node * 16 + sl];
  float2 gv = g2[node];
  float ga0 = d * gv.x, ga1 = d * gv.y;
  int e = rowptr[node], end = rowptr[node + 1];
  for (; e < end; ++e) {
    int s = csr_src[e];
    float w = dis[s];
    acc = fmaf(w, Y[(size_t)s * 16 + sl], acc);
    float2 gu = g2[s];
    ga0 = fmaf(w, gu.x, ga0);
    ga1 = fmaf(w, gu.y, ga1);
  }
  out[(size_t)node * 16 + sl] = d * acc + sm[SM_CLSC + sl];
  if (sl == 0)
    ((float2*)gout)[node] =
        make_float2(d * ga0 + sm[SM_C2 + 0], d * ga1 + sm[SM_C2 + 1]);
}

// g_out = A'(g_in) + cadd  (2 feats, thread per node); FINAL adds sigmoid
template <int FINAL>
__global__ __launch_bounds__(256) void k_agg2(
    const float* __restrict__ gin, const int* __restrict__ rowptr,
    const int* __restrict__ csr_src, const float* __restrict__ dis,
    const float* __restrict__ cadd, float* __restrict__ gout, int N) {
  int i = blockIdx.x * 256 + threadIdx.x;
  if (i >= N) return;
  const float2* g2 = (const float2*)gin;
  float d = dis[i];
  float2 v = g2[i];
  float a0 = d * v.x, a1 = d * v.y;
  int e = rowptr[i], end = rowptr[i + 1];
  for (; e < end; ++e) {
    int s = csr_src[e];
    float w = dis[s];
    float2 u = g2[s];
    a0 = fmaf(w, u.x, a0); a1 = fmaf(w, u.y, a1);
  }
  a0 = d * a0 + cadd[0]; a1 = d * a1 + cadd[1];
  if (FINAL) {
    a0 = 1.f / (1.f + expf(-a0));
    a1 = 1.f / (1.f + expf(-a1));
  }
  ((float2*)gout)[i] = make_float2(a0, a1);
}

extern "C" void kernel_launch(void* const* d_in, const int* in_sizes, int n_in,
                              void* d_out, int out_size, void* d_ws, size_t ws_size,
                              hipStream_t stream) {
  const float* x = (const float*)d_in[0];
  const int* ei = (const int*)d_in[1];   // int32
  const float* W1 = (const float*)d_in[2];
  const float* b1 = (const float*)d_in[3];
  const float* W2 = (const float*)d_in[4];
  const float* b2 = (const float*)d_in[5];
  const float* Wc = (const float*)d_in[6];
  const float* bc = (const float*)d_in[7];
  const float* We1 = (const float*)d_in[8];
  const float* be1 = (const float*)d_in[9];
  const float* We2 = (const float*)d_in[10];
  const float* be2 = (const float*)d_in[11];
  const float* We3 = (const float*)d_in[12];
  const float* be3 = (const float*)d_in[13];
  const float* We4 = (const float*)d_in[14];
  const float* be4 = (const float*)d_in[15];
  const float* Wt = (const float*)d_in[16];
  const float* bt = (const float*)d_in[17];
  float* out = (float*)d_out;

  const int N = in_sizes[0] / 128;
  const int E = in_sizes[1] / 2;
  const int NB = (N + 1023) / 1024;      // scan blocks (<=128)

  char* ws = (char*)d_ws;
  size_t off = 0;
  auto alloc = [&](size_t bytes) {
    size_t o = off;
    off = (off + bytes + 255) & ~(size_t)255;
    return o;
  };
  int* deg = (int*)(ws + alloc((size_t)N * 4));
  int* cnt = (int*)(ws + alloc((size_t)N * 4));
  int* rowptr = (int*)(ws + alloc(((size_t)N + 1) * 4));
  int* bsum = (int*)(ws + alloc(128 * 4));
  float* dis = (float*)(ws + alloc((size_t)N * 4));
  int* csr_src = (int*)(ws + alloc((size_t)E * 4));
  unsigned short* axh = (unsigned short*)(ws + alloc((size_t)N * 128 * 2));
  unsigned short* axl = (unsigned short*)(ws + alloc((size_t)N * 128 * 2));
  float* y16 = (float*)(ws + alloc((size_t)N * 16 * 4));
  float* ga = (float*)(ws + alloc((size_t)N * 2 * 4));
  float* gb = (float*)(ws + alloc((size_t)N * 2 * 4));
  float* sm = (float*)(ws + alloc((size_t)SM_TOTAL * 4));
  unsigned short* w1h = (unsigned short*)(ws + alloc(32768 * 2));
  unsigned short* w1l = (unsigned short*)(ws + alloc(32768 * 2));
  unsigned short* w2h = (unsigned short*)(ws + alloc(4096 * 2));
  unsigned short* w2l = (unsigned short*)(ws + alloc(4096 * 2));

  hipMemsetAsync(deg, 0, (size_t)N * 4, stream);

  k_precompute<<<33, 256, 0, stream>>>(W1, W2, b2, Wc, bc, We1, be1, We2, be2,
                                       We3, be3, We4, be4, Wt, bt, sm,
                                       w1h, w1l, w2h, w2l);
  k_deg<<<(E + 255) / 256, 256, 0, stream>>>(ei, deg, E, N);
  k_scan1<<<NB, 1024, 0, stream>>>(deg, rowptr, bsum, dis, cnt, N);
  k_scan2<<<1, 128, 0, stream>>>(bsum, rowptr, NB);
  k_scan3<<<(N + 255) / 256, 256, 0, stream>>>(rowptr, bsum, N);
  k_scatter<<<(E + 255) / 256, 256, 0, stream>>>(ei, rowptr, cnt, csr_src, E, N);
  k_agg128<<<(N + 3) / 4, 256, 0, stream>>>(x, rowptr, csr_src, dis, sm,
                                            axh, axl, ga, N);
  k_gemm_mfma<<<(N + 63) / 64, 256, 0, stream>>>(axh, axl, w1h, w1l, w2h, w2l,
                                                 b1, y16, N);
  k_agg18<<<(N + 15) / 16, 256, 0, stream>>>(y16, ga, rowptr, csr_src, dis, sm,
                                             out, gb, N);
  k_agg2<0><<<(N + 255) / 256, 256, 0, stream>>>(gb, rowptr, csr_src, dis,
                                                 sm + SM_C3, ga, N);
  k_agg2<1><<<(N + 255) / 256, 256, 0, stream>>>(
      ga, rowptr, csr_src, dis, sm + SM_FC, out + (size_t)N * 16, N);
}

// Round 7
// 581.391 us; speedup vs baseline: 1.0337x; 1.0337x over previous
//
#include <hip/hip_runtime.h>
#include <hip/hip_fp16.h>
#include <math.h>

// ---------------------------------------------------------------------------
// GCN dual-branch, algebraically restructured:
//   ax = A'x  (128 feats)            [A' = D^-1/2 (A+I) D^-1/2]
//   branch1: y16 = relu(ax@W1 + b1) @ (W2@Wc); cls = A'(y16) + (b2@Wc+bc)
//   branch2 (fully linear): g1 = ax@Me + c1 ; g_{k+1} = A'(g_k) + c_{k+1}
//            trust = sigmoid(A'(g3) + be4@Wt + bt)
// A'v|_i = d_i*(d_i*v_i + sum dis[s]*v_s) -- edge weights never materialized.
// x gathered in fp16 (halves agg128 traffic); GEMM on MFMA via split-bf16.
// edge_index is INT32.
// ---------------------------------------------------------------------------

#define SM_W2C   0        // 256*16
#define SM_T4    4096     // 128*2
#define SM_T3    4352
#define SM_T2    4608
#define SM_ME    4864
#define SM_CLSC  5120     // 16
#define SM_C1    5136     // 2
#define SM_C2    5138
#define SM_C3    5140
#define SM_FC    5142     // 2  (be4@Wt + bt)
#define SM_TOTAL 5248

typedef __attribute__((ext_vector_type(8))) short bf16x8;
typedef __attribute__((ext_vector_type(4))) float f32x4;
#define MFMA16(a, b, c) __builtin_amdgcn_mfma_f32_16x16x32_bf16(a, b, c, 0, 0, 0)

__device__ inline unsigned short f2bf(float f) {  // RNE f32 -> bf16 bits
  unsigned u = __float_as_uint(f);
  u += 0x7fffu + ((u >> 16) & 1u);
  return (unsigned short)(u >> 16);
}
__device__ inline float bf2f(unsigned short h) {
  return __uint_as_float((unsigned)h << 16);
}

__global__ __launch_bounds__(256) void k_deg(const int* __restrict__ ei,
                                             int* __restrict__ deg, int E, int N) {
  int e = blockIdx.x * 256 + threadIdx.x;
  if (e < E) {
    unsigned c = (unsigned)ei[E + e];
    if (c >= (unsigned)N) c = 0;
    atomicAdd(&deg[c], 1);
  }
}

// phase 1: per-block inclusive scan of deg -> rowptr[i+1] (pre-offset),
// block totals -> bsum; fused dis = rsqrt(deg+1) and cnt=0.
__global__ __launch_bounds__(1024) void k_scan1(const int* __restrict__ deg,
                                                int* __restrict__ rowptr,
                                                int* __restrict__ bsum,
                                                float* __restrict__ dis,
                                                int* __restrict__ cnt, int n) {
  __shared__ int wsum[16];
  int tid = threadIdx.x, lane = tid & 63, wid = tid >> 6;
  int i = blockIdx.x * 1024 + tid;
  int v = (i < n) ? deg[i] : 0;
  if (i < n) {
    dis[i] = 1.0f / sqrtf((float)v + 1.0f);
    cnt[i] = 0;
  }
  int x = v;
  #pragma unroll
  for (int off = 1; off < 64; off <<= 1) {
    int t = __shfl_up(x, off, 64);
    if (lane >= off) x += t;
  }
  if (lane == 63) wsum[wid] = x;
  __syncthreads();
  if (wid == 0 && lane < 16) {
    int ws = wsum[lane];
    #pragma unroll
    for (int off = 1; off < 16; off <<= 1) {
      int t = __shfl_up(ws, off, 64);
      if (lane >= off) ws += t;
    }
    wsum[lane] = ws;
  }
  __syncthreads();
  int incl = x + (wid ? wsum[wid - 1] : 0);
  if (i < n) rowptr[i + 1] = incl;
  if (tid == 0) bsum[blockIdx.x] = wsum[15];
}

__global__ __launch_bounds__(128) void k_scan2(int* __restrict__ bsum,
                                               int* __restrict__ rowptr, int B) {
  __shared__ int s[128];
  int tid = threadIdx.x;
  s[tid] = (tid < B) ? bsum[tid] : 0;
  __syncthreads();
  if (tid == 0) {
    int acc = 0;
    for (int j = 0; j < B; ++j) { int t = s[j]; s[j] = acc; acc += t; }
    rowptr[0] = 0;
  }
  __syncthreads();
  if (tid < B) bsum[tid] = s[tid];
}

__global__ __launch_bounds__(256) void k_scan3(int* __restrict__ rowptr,
                                               const int* __restrict__ bsum, int n) {
  int i = blockIdx.x * 256 + threadIdx.x;
  if (i < n) rowptr[i + 1] += bsum[i >> 10];
}

__global__ __launch_bounds__(256) void k_scatter(const int* __restrict__ ei,
                                                 const int* __restrict__ rowptr,
                                                 int* __restrict__ cnt,
                                                 int* __restrict__ csr_src,
                                                 int E, int N) {
  int e = blockIdx.x * 256 + threadIdx.x;
  if (e >= E) return;
  unsigned r = (unsigned)ei[e];
  unsigned c = (unsigned)ei[E + e];
  if (r >= (unsigned)N) r = 0;
  if (c >= (unsigned)N) c = 0;
  int pos = rowptr[c] + atomicAdd(&cnt[c], 1);
  csr_src[pos] = (int)r;
}

// fold weight chains + bf16 hi/lo splits + x->fp16 convert.
// Grid = 33 + CVB blocks:
//   [0,16): W2C rows; [16,32): W1 split; 32: serial chains; [33,..): x->fp16
__global__ __launch_bounds__(256) void k_precompute(
    const float* __restrict__ x, unsigned* __restrict__ xh, int NP4,
    const float* __restrict__ W1,
    const float* __restrict__ W2, const float* __restrict__ b2,
    const float* __restrict__ Wc, const float* __restrict__ bc,
    const float* __restrict__ We1, const float* __restrict__ be1,
    const float* __restrict__ We2, const float* __restrict__ be2,
    const float* __restrict__ We3, const float* __restrict__ be3,
    const float* __restrict__ We4, const float* __restrict__ be4,
    const float* __restrict__ Wt, const float* __restrict__ bt,
    float* __restrict__ sm,
    unsigned short* __restrict__ w1h, unsigned short* __restrict__ w1l,
    unsigned short* __restrict__ w2h, unsigned short* __restrict__ w2l,
    int nblk) {
  int tid = threadIdx.x, b = blockIdx.x;
  if (b >= 33) {
    // x -> packed fp16 (uint4 = 8 floats per chunk)
    const float4* xf4 = (const float4*)x;
    uint4* xh4 = (uint4*)xh;
    int nthreads = (nblk - 33) * 256;
    for (int c = (b - 33) * 256 + tid; c < NP4; c += nthreads) {
      float4 a = xf4[2 * c], d = xf4[2 * c + 1];
      __half2 h0 = __floats2half2_rn(a.x, a.y);
      __half2 h1 = __floats2half2_rn(a.z, a.w);
      __half2 h2 = __floats2half2_rn(d.x, d.y);
      __half2 h3 = __floats2half2_rn(d.z, d.w);
      uint4 o;
      o.x = *(unsigned*)&h0; o.y = *(unsigned*)&h1;
      o.z = *(unsigned*)&h2; o.w = *(unsigned*)&h3;
      xh4[c] = o;
    }
    return;
  }
  if (b < 16) {
    int r = b * 16 + (tid >> 4), c = tid & 15;
    float s = 0.f;
    #pragma unroll 4
    for (int k = 0; k < 128; ++k) s += W2[(size_t)r * 128 + k] * Wc[k * 16 + c];
    sm[SM_W2C + r * 16 + c] = s;
    unsigned short h = f2bf(s);
    w2h[c * 256 + r] = h;                 // w2t[c][k=r]
    w2l[c * 256 + r] = f2bf(s - bf2f(h));
    return;
  }
  if (b < 32) {
    int base = (b - 16) * 2048;
    #pragma unroll
    for (int it = 0; it < 8; ++it) {
      int idx = base + it * 256 + tid;    // w1t[c][k]
      int c = idx >> 7, k = idx & 127;
      float v = W1[(size_t)k * 256 + c];
      unsigned short h = f2bf(v);
      w1h[idx] = h;
      w1l[idx] = f2bf(v - bf2f(h));
    }
    return;
  }
  // b == 32: chains
  {
    int r = tid >> 1, c = tid & 1; float s = 0.f;
    for (int k = 0; k < 128; ++k) s += We4[r * 128 + k] * Wt[k * 2 + c];
    sm[SM_T4 + r * 2 + c] = s;
  }
  __syncthreads();
  {
    int r = tid >> 1, c = tid & 1; float s = 0.f;
    for (int k = 0; k < 128; ++k) s += We3[r * 128 + k] * sm[SM_T4 + k * 2 + c];
    sm[SM_T3 + r * 2 + c] = s;
  }
  __syncthreads();
  {
    int r = tid >> 1, c = tid & 1; float s = 0.f;
    for (int k = 0; k < 128; ++k) s += We2[r * 128 + k] * sm[SM_T3 + k * 2 + c];
    sm[SM_T2 + r * 2 + c] = s;
  }
  __syncthreads();
  {
    int r = tid >> 1, c = tid & 1; float s = 0.f;
    for (int k = 0; k < 128; ++k) s += We1[r * 128 + k] * sm[SM_T2 + k * 2 + c];
    sm[SM_ME + r * 2 + c] = s;
  }
  if (tid < 16) {
    float s = 0.f;
    for (int k = 0; k < 128; ++k) s += b2[k] * Wc[k * 16 + tid];
    sm[SM_CLSC + tid] = s + bc[tid];
  }
  __syncthreads();
  if (tid < 2) {
    float s = 0.f;
    for (int k = 0; k < 128; ++k) s += be1[k] * sm[SM_T2 + k * 2 + tid];
    sm[SM_C1 + tid] = s;
    s = 0.f;
    for (int k = 0; k < 128; ++k) s += be2[k] * sm[SM_T3 + k * 2 + tid];
    sm[SM_C2 + tid] = s;
    s = 0.f;
    for (int k = 0; k < 128; ++k) s += be3[k] * sm[SM_T4 + k * 2 + tid];
    sm[SM_C3 + tid] = s;
    s = 0.f;
    for (int k = 0; k < 128; ++k) s += be4[k] * Wt[k * 2 + tid];
    sm[SM_FC + tid] = s + bt[tid];
  }
}

// ax = A'x (wave per node), fp16 gather, bf16 hi/lo out; fused g1 = ax@Me + c1
__global__ __launch_bounds__(256) void k_agg128(
    const unsigned* __restrict__ xh, const int* __restrict__ rowptr,
    const int* __restrict__ csr_src, const float* __restrict__ dis,
    const float* __restrict__ sm,
    unsigned short* __restrict__ axh, unsigned short* __restrict__ axl,
    float* __restrict__ ga, int N) {
  int node = blockIdx.x * 4 + (threadIdx.x >> 6);
  if (node >= N) return;
  int lane = threadIdx.x & 63;
  float d = dis[node];
  unsigned su = xh[(size_t)node * 64 + lane];
  float2 sv = __half22float2(*(__half2*)&su);
  float a0 = d * sv.x, a1 = d * sv.y;
  int e = rowptr[node], end = rowptr[node + 1];
  while (e < end) {
    int rem = end - e;
    int cnt = rem < 64 ? rem : 64;
    int off = lane < cnt ? lane : cnt - 1;
    int src_l = csr_src[e + off];
    int wbits = __float_as_int(dis[src_l]);
    for (int i = 0; i < cnt; ++i) {
      int s = __builtin_amdgcn_readlane(src_l, i);
      float w = __int_as_float(__builtin_amdgcn_readlane(wbits, i));
      unsigned u = xh[(size_t)s * 64 + lane];
      float2 uf = __half22float2(*(__half2*)&u);
      a0 = fmaf(w, uf.x, a0);
      a1 = fmaf(w, uf.y, a1);
    }
    e += 64;
  }
  a0 *= d; a1 *= d;
  unsigned short h0 = f2bf(a0), h1v = f2bf(a1);
  unsigned short l0 = f2bf(a0 - bf2f(h0)), l1 = f2bf(a1 - bf2f(h1v));
  ((unsigned int*)axh)[(size_t)node * 64 + lane] = (unsigned)h0 | ((unsigned)h1v << 16);
  ((unsigned int*)axl)[(size_t)node * 64 + lane] = (unsigned)l0 | ((unsigned)l1 << 16);
  float4 me = *(const float4*)&sm[SM_ME + lane * 4];
  float p0 = a0 * me.x + a1 * me.z;
  float p1 = a0 * me.y + a1 * me.w;
  #pragma unroll
  for (int m = 32; m; m >>= 1) { p0 += __shfl_xor(p0, m); p1 += __shfl_xor(p1, m); }
  if (lane == 0)
    ((float2*)ga)[node] = make_float2(p0 + sm[SM_C1 + 0], p1 + sm[SM_C1 + 1]);
}

// y16 = relu(ax@W1 + b1) @ W2c via split-bf16 MFMA (layouts verified in R4).
__global__ __launch_bounds__(256, 2) void k_gemm_mfma(
    const unsigned short* __restrict__ axh, const unsigned short* __restrict__ axl,
    const unsigned short* __restrict__ w1h, const unsigned short* __restrict__ w1l,
    const unsigned short* __restrict__ w2h, const unsigned short* __restrict__ w2l,
    const float* __restrict__ b1, float* __restrict__ Y, int N) {
  __shared__ unsigned short lds[32768];  // 64 KB
  int tid = threadIdx.x, lane = tid & 63, w = tid >> 6;
  int r16 = lane & 15, kh = lane >> 4;
  int m0 = blockIdx.x * 64;
  #pragma unroll
  for (int it = 0; it < 8; ++it) {
    int idx = it * 256 + tid;            // 0..2047 chunks of 16B
    int arr = idx >> 10, rem = idx & 1023;
    int row = rem >> 4, ch = rem & 15;
    int gr = m0 + row; if (gr > N - 1) gr = N - 1;
    const unsigned short* src = (arr ? axl : axh) + (size_t)gr * 128 + ch * 8;
    uint4 vv = *(const uint4*)src;
    *(uint4*)&lds[arr * 8192 + row * 128 + ((ch ^ (row & 7)) * 8)] = vv;
  }
  __syncthreads();
  f32x4 acc[4][4];
  #pragma unroll
  for (int i = 0; i < 4; ++i)
    #pragma unroll
    for (int j = 0; j < 4; ++j) acc[i][j] = (f32x4){0.f, 0.f, 0.f, 0.f};
  #pragma unroll
  for (int ks = 0; ks < 4; ++ks) {
    bf16x8 bh[4], bl[4];
    #pragma unroll
    for (int nt = 0; nt < 4; ++nt) {
      int col = w * 64 + nt * 16 + r16;
      size_t boff = (size_t)col * 128 + ks * 32 + kh * 8;
      bh[nt] = *(const bf16x8*)(w1h + boff);
      bl[nt] = *(const bf16x8*)(w1l + boff);
    }
    #pragma unroll
    for (int mt = 0; mt < 4; ++mt) {
      int row = mt * 16 + r16;
      int ch = ks * 4 + kh;
      int off = row * 128 + ((ch ^ (row & 7)) * 8);
      bf16x8 ah = *(const bf16x8*)&lds[off];
      bf16x8 al = *(const bf16x8*)&lds[8192 + off];
      #pragma unroll
      for (int nt = 0; nt < 4; ++nt) {
        acc[mt][nt] = MFMA16(ah, bh[nt], acc[mt][nt]);
        acc[mt][nt] = MFMA16(ah, bl[nt], acc[mt][nt]);
        acc[mt][nt] = MFMA16(al, bh[nt], acc[mt][nt]);
      }
    }
  }
  __syncthreads();
  #pragma unroll
  for (int nt = 0; nt < 4; ++nt) {
    int colL = w * 64 + nt * 16 + r16;
    float bv = b1[colL];
    #pragma unroll
    for (int mt = 0; mt < 4; ++mt) {
      #pragma unroll
      for (int r = 0; r < 4; ++r) {
        int rowL = mt * 16 + kh * 4 + r;
        float vv = acc[mt][nt][r] + bv;
        vv = vv > 0.f ? vv : 0.f;
        unsigned short hh = f2bf(vv);
        unsigned short ll = f2bf(vv - bf2f(hh));
        int idx = rowL * 256 + (colL ^ ((rowL & 7) << 3));
        lds[idx] = hh;
        lds[16384 + idx] = ll;
      }
    }
  }
  __syncthreads();
  f32x4 y = (f32x4){0.f, 0.f, 0.f, 0.f};
  int rowL = w * 16 + r16;
  #pragma unroll
  for (int k2 = 0; k2 < 8; ++k2) {
    int cb = k2 * 32 + kh * 8;
    int idx = rowL * 256 + (cb ^ ((rowL & 7) << 3));
    bf16x8 a2h = *(const bf16x8*)&lds[idx];
    bf16x8 a2l = *(const bf16x8*)&lds[16384 + idx];
    size_t boff = (size_t)r16 * 256 + cb;
    bf16x8 b2h = *(const bf16x8*)(w2h + boff);
    bf16x8 b2l = *(const bf16x8*)(w2l + boff);
    y = MFMA16(a2h, b2h, y);
    y = MFMA16(a2h, b2l, y);
    y = MFMA16(a2l, b2h, y);
  }
  #pragma unroll
  for (int r = 0; r < 4; ++r) {
    int gr = m0 + w * 16 + kh * 4 + r;
    if (gr < N) Y[(size_t)gr * 16 + r16] = y[r];
  }
}

// fused: cls = A'(y16) + cls_const -> out, AND gb = A'(ga) + c2 -> gout.
// 64 lanes per node: 4 edges in flight (eo=lane>>4) x 16 feats (sl).
__global__ __launch_bounds__(256) void k_agg18(
    const float* __restrict__ Y, const float* __restrict__ g,
    const int* __restrict__ rowptr, const int* __restrict__ csr_src,
    const float* __restrict__ dis, const float* __restrict__ sm,
    float* __restrict__ out, float* __restrict__ gout, int N) {
  int node = blockIdx.x * 4 + (threadIdx.x >> 6);
  if (node >= N) return;
  int lane = threadIdx.x & 63;
  int eo = lane >> 4, sl = lane & 15;
  const float2* g2 = (const float2*)g;
  float d = dis[node];
  float acc = 0.f, ga0 = 0.f, ga1 = 0.f;
  if (eo == 0) {
    acc = d * Y[(size_t)node * 16 + sl];
    float2 gv = g2[node];
    ga0 = d * gv.x; ga1 = d * gv.y;
  }
  int end = rowptr[node + 1];
  for (int e = rowptr[node] + eo; e < end; e += 4) {
    int s = csr_src[e];
    float w = dis[s];
    acc = fmaf(w, Y[(size_t)s * 16 + sl], acc);
    float2 gu = g2[s];
    ga0 = fmaf(w, gu.x, ga0);
    ga1 = fmaf(w, gu.y, ga1);
  }
  acc += __shfl_xor(acc, 16); acc += __shfl_xor(acc, 32);
  ga0 += __shfl_xor(ga0, 16); ga0 += __shfl_xor(ga0, 32);
  ga1 += __shfl_xor(ga1, 16); ga1 += __shfl_xor(ga1, 32);
  if (lane < 16) out[(size_t)node * 16 + sl] = d * acc + sm[SM_CLSC + sl];
  if (lane == 0)
    ((float2*)gout)[node] =
        make_float2(d * ga0 + sm[SM_C2 + 0], d * ga1 + sm[SM_C2 + 1]);
}

// g_out = A'(g_in) + cadd; 8 lanes per node (8 edges in flight); FINAL: sigmoid
template <int FINAL>
__global__ __launch_bounds__(256) void k_agg2(
    const float* __restrict__ gin, const int* __restrict__ rowptr,
    const int* __restrict__ csr_src, const float* __restrict__ dis,
    const float* __restrict__ cadd, float* __restrict__ gout, int N) {
  int i = blockIdx.x * 32 + (threadIdx.x >> 3);
  if (i >= N) return;
  int el = threadIdx.x & 7;
  const float2* g2 = (const float2*)gin;
  float d = dis[i];
  float a0 = 0.f, a1 = 0.f;
  if (el == 0) {
    float2 v = g2[i];
    a0 = d * v.x; a1 = d * v.y;
  }
  int end = rowptr[i + 1];
  for (int e = rowptr[i] + el; e < end; e += 8) {
    int s = csr_src[e];
    float w = dis[s];
    float2 u = g2[s];
    a0 = fmaf(w, u.x, a0); a1 = fmaf(w, u.y, a1);
  }
  #pragma unroll
  for (int m = 1; m < 8; m <<= 1) {
    a0 += __shfl_xor(a0, m); a1 += __shfl_xor(a1, m);
  }
  if (el == 0) {
    a0 = d * a0 + cadd[0]; a1 = d * a1 + cadd[1];
    if (FINAL) {
      a0 = 1.f / (1.f + expf(-a0));
      a1 = 1.f / (1.f + expf(-a1));
    }
    ((float2*)gout)[i] = make_float2(a0, a1);
  }
}

extern "C" void kernel_launch(void* const* d_in, const int* in_sizes, int n_in,
                              void* d_out, int out_size, void* d_ws, size_t ws_size,
                              hipStream_t stream) {
  const float* x = (const float*)d_in[0];
  const int* ei = (const int*)d_in[1];   // int32
  const float* W1 = (const float*)d_in[2];
  const float* b1 = (const float*)d_in[3];
  const float* W2 = (const float*)d_in[4];
  const float* b2 = (const float*)d_in[5];
  const float* Wc = (const float*)d_in[6];
  const float* bc = (const float*)d_in[7];
  const float* We1 = (const float*)d_in[8];
  const float* be1 = (const float*)d_in[9];
  const float* We2 = (const float*)d_in[10];
  const float* be2 = (const float*)d_in[11];
  const float* We3 = (const float*)d_in[12];
  const float* be3 = (const float*)d_in[13];
  const float* We4 = (const float*)d_in[14];
  const float* be4 = (const float*)d_in[15];
  const float* Wt = (const float*)d_in[16];
  const float* bt = (const float*)d_in[17];
  float* out = (float*)d_out;

  const int N = in_sizes[0] / 128;
  const int E = in_sizes[1] / 2;
  const int NB = (N + 1023) / 1024;      // scan blocks (<=128)
  const int NP4 = N * 128 / 8;           // fp16 convert chunks (uint4)
  const int CVB = 1600;                  // convert blocks appended to precompute

  char* ws = (char*)d_ws;
  size_t off = 0;
  auto alloc = [&](size_t bytes) {
    size_t o = off;
    off = (off + bytes + 255) & ~(size_t)255;
    return o;
  };
  int* deg = (int*)(ws + alloc((size_t)N * 4));
  int* cnt = (int*)(ws + alloc((size_t)N * 4));
  int* rowptr = (int*)(ws + alloc(((size_t)N + 1) * 4));
  int* bsum = (int*)(ws + alloc(128 * 4));
  float* dis = (float*)(ws + alloc((size_t)N * 4));
  int* csr_src = (int*)(ws + alloc((size_t)E * 4));
  unsigned* xh = (unsigned*)(ws + alloc((size_t)N * 128 * 2));
  unsigned short* axh = (unsigned short*)(ws + alloc((size_t)N * 128 * 2));
  unsigned short* axl = (unsigned short*)(ws + alloc((size_t)N * 128 * 2));
  float* y16 = (float*)(ws + alloc((size_t)N * 16 * 4));
  float* ga = (float*)(ws + alloc((size_t)N * 2 * 4));
  float* gb = (float*)(ws + alloc((size_t)N * 2 * 4));
  float* sm = (float*)(ws + alloc((size_t)SM_TOTAL * 4));
  unsigned short* w1h = (unsigned short*)(ws + alloc(32768 * 2));
  unsigned short* w1l = (unsigned short*)(ws + alloc(32768 * 2));
  unsigned short* w2h = (unsigned short*)(ws + alloc(4096 * 2));
  unsigned short* w2l = (unsigned short*)(ws + alloc(4096 * 2));

  hipMemsetAsync(deg, 0, (size_t)N * 4, stream);

  k_precompute<<<33 + CVB, 256, 0, stream>>>(
      x, xh, NP4, W1, W2, b2, Wc, bc, We1, be1, We2, be2, We3, be3, We4, be4,
      Wt, bt, sm, w1h, w1l, w2h, w2l, 33 + CVB);
  k_deg<<<(E + 255) / 256, 256, 0, stream>>>(ei, deg, E, N);
  k_scan1<<<NB, 1024, 0, stream>>>(deg, rowptr, bsum, dis, cnt, N);
  k_scan2<<<1, 128, 0, stream>>>(bsum, rowptr, NB);
  k_scan3<<<(N + 255) / 256, 256, 0, stream>>>(rowptr, bsum, N);
  k_scatter<<<(E + 255) / 256, 256, 0, stream>>>(ei, rowptr, cnt, csr_src, E, N);
  k_agg128<<<(N + 3) / 4, 256, 0, stream>>>(xh, rowptr, csr_src, dis, sm,
                                            axh, axl, ga, N);
  k_gemm_mfma<<<(N + 63) / 64, 256, 0, stream>>>(axh, axl, w1h, w1l, w2h, w2l,
                                                 b1, y16, N);
  k_agg18<<<(N + 3) / 4, 256, 0, stream>>>(y16, ga, rowptr, csr_src, dis, sm,
                                           out, gb, N);
  k_agg2<0><<<(N + 31) / 32, 256, 0, stream>>>(gb, rowptr, csr_src, dis,
                                               sm + SM_C3, ga, N);
  k_agg2<1><<<(N + 31) / 32, 256, 0, stream>>>(
      ga, rowptr, csr_src, dis, sm + SM_FC, out + (size_t)N * 16, N);
}